// Round 2
// baseline (1617.254 us; speedup 1.0000x reference)
//
#include <hip/hip_runtime.h>

typedef __bf16 bf16;
typedef __bf16 bf16x8 __attribute__((ext_vector_type(8)));
typedef float f32x4 __attribute__((ext_vector_type(4)));

#define N_DSTN 8192
#define TT 16
#define XROW 40   // xbuf row stride in shorts: [x(16) | zeros(16) | pad(8)]
#define HROW 72   // h/hsrc row stride in shorts: [h(64) | pad(8)]

__device__ __forceinline__ float sigf(float x) {
    float e = __builtin_amdgcn_exp2f(-1.44269504f * x);
    return __builtin_amdgcn_rcpf(1.0f + e);
}
__device__ __forceinline__ float tanh_fast(float x) {
    float e = __builtin_amdgcn_exp2f(2.88539008f * x);
    return 1.0f - 2.0f * __builtin_amdgcn_rcpf(1.0f + e);
}
__device__ __forceinline__ f32x4 MFMA(bf16x8 a, bf16x8 b, f32x4 c) {
    return __builtin_amdgcn_mfma_f32_16x16x32_bf16(a, b, c, 0, 0, 0);
}
// dtype-agnostic float load: isb ? bf16[i] : f32[i]
__device__ __forceinline__ float ldf(const void* p, long i, bool isb) {
    return isb ? (float)((const bf16*)p)[i] : ((const float*)p)[i];
}

extern "C" __global__ void __launch_bounds__(256, 2)
gtea_fused(const void* __restrict__ node_features,   // 0  (16384,64)
           const void* __restrict__ edge_feats,      // 1  (E,16,8)
           const void* __restrict__ e_times,         // 2  (E,16)
           const int*  __restrict__ e_len,           // 3  (E,)
           const int*  __restrict__ edge_src,        // 4  (E,)
           const void* __restrict__ t2v_w,           // 5  (7,)
           const void* __restrict__ t2v_b,           // 6  (7,)
           const void* __restrict__ t2v_w0,          // 7  (1,)
           const void* __restrict__ t2v_b0,          // 8  (1,)
           const void* __restrict__ Wih_e,           // 9  (256,16)
           const void* __restrict__ Whh_e,           // 10 (256,64)
           const void* __restrict__ bih_e,           // 11 (256,)
           const void* __restrict__ bhh_e,           // 12 (256,)
           const void* __restrict__ Wih_a,           // 13
           const void* __restrict__ Whh_a,           // 14
           const void* __restrict__ bih_a,           // 15
           const void* __restrict__ bhh_a,           // 16
           const void* __restrict__ attn_w,          // 17 (64,)
           const void* __restrict__ edge_out_W,      // 18 (64,128)
           const void* __restrict__ edge_out_b,      // 19 (64,)
           const void* __restrict__ node_W,          // 20 (64,128)
           const void* __restrict__ node_b,          // 21 (64,)
           void* __restrict__ outp)                  // (8192,64)
{
    __shared__ __align__(16) bf16 xbuf[TT * 32 * XROW];   // 40960 B
    __shared__ __align__(16) bf16 habuf[2][32 * HROW];    // 9216 B
    __shared__ __align__(16) bf16 hsrc[32 * HROW];        // 4608 B
    __shared__ float scores_sh[32];
    __shared__ float alpha_sh[32];
    __shared__ float t2w[8], t2b[8];
    __shared__ float attn_f[64];
    __shared__ float vbuf[128];
    __shared__ float part_sh[4 * 64];
    __shared__ int   len_sh[32];
    __shared__ int   isb_sh;

    const int tid = threadIdx.x;
    const int w   = tid >> 6;
    const int l   = tid & 63;
    const int l15 = l & 15;
    const int q   = l >> 4;
    const int u16 = 16 * w + l15;

    const int d  = blockIdx.x;
    const int e0 = d * 32;

    // ---------------- dtype sniff (wave 0) ----------------
    // e_times is uniform[0,1): as bf16 every u16 <= 0x3F80; as f32 the low
    // half-words are ~uniform random -> ballot fails with P ~ 1-1e-39.
    if (tid < 64) {
        const unsigned short* u = (const unsigned short*)e_times;
        unsigned short a = u[tid * 2], b = u[tid * 2 + 1];
        bool ok = (a <= 0x3F80u) && (b <= 0x3F80u);
        unsigned long long m = __ballot(ok);
        if (tid == 0) isb_sh = (m == ~0ULL) ? 1 : 0;
    }
    __syncthreads();
    const bool isb = (isb_sh != 0);

    // ---------------- staging ----------------
    if (tid < 7) { t2w[tid] = ldf(t2v_w, tid, isb); t2b[tid] = ldf(t2v_b, tid, isb); }
    if (tid == 7) { t2w[7] = ldf(t2v_w0, 0, isb); t2b[7] = ldf(t2v_b0, 0, isb); }
    if (tid < 64) attn_f[tid] = ldf(attn_w, tid, isb);
    if (tid < 32) len_sh[tid] = e_len[e0 + tid];
    if (tid < 64) vbuf[tid] = ldf(node_features, (long)d * 64 + tid, isb);
    {   // gather h_src rows: 8 threads x 8 elts per edge
        int j = tid >> 3, c8 = tid & 7;
        int src = edge_src[e0 + j];
        #pragma unroll
        for (int ii = 0; ii < 8; ii++)
            hsrc[j * HROW + c8 * 8 + ii] = (bf16)ldf(node_features, (long)src * 64 + c8 * 8 + ii, isb);
    }
    {   // zero h buffers (h0 = 0)
        unsigned int* hz = reinterpret_cast<unsigned int*>(&habuf[0][0]);
        for (int i = tid; i < 2 * 32 * HROW / 2; i += 256) hz[i] = 0u;
    }
    __syncthreads();   // t2w/t2b ready

    // xbuf: per (edge j, t): [edge_feats(8) | sin(7) | lin(1) | zeros(16)]
    for (int pid = tid; pid < 512; pid += 256) {
        int j = pid >> 4, t = pid & 15;
        bf16* row = &xbuf[(t * 32 + j) * XROW];
        long base = ((long)(e0 + j) * TT + t) * 8;
        #pragma unroll
        for (int ii = 0; ii < 8; ii++)
            row[ii] = (bf16)ldf(edge_feats, base + ii, isb);
        float tau = ldf(e_times, (long)(e0 + j) * TT + t, isb);
        #pragma unroll
        for (int i = 0; i < 7; i++) row[8 + i] = (bf16)__sinf(tau * t2w[i] + t2b[i]);
        row[15] = (bf16)(tau * t2w[7] + t2b[7]);
        #pragma unroll
        for (int i = 16; i < 32; i++) row[i] = (bf16)0.0f;
    }

    // ---------------- weight fragments (registers, invariant over t) ----------------
    const void* WhhP[2] = {Whh_e, Whh_a};
    const void* WihP[2] = {Wih_e, Wih_a};
    const void* bihP[2] = {bih_e, bih_a};
    const void* bhhP[2] = {bhh_e, bhh_a};

    bf16x8 Bh[2][4][2];
    bf16x8 Bx[2][4];
    float  bias[2][4];
    #pragma unroll
    for (int L = 0; L < 2; L++) {
        #pragma unroll
        for (int j = 0; j < 4; j++) {
            int n = 64 * j + u16;
            #pragma unroll
            for (int ks = 0; ks < 2; ks++)
                #pragma unroll
                for (int ii = 0; ii < 8; ii++)
                    Bh[L][j][ks][ii] = (bf16)ldf(WhhP[L], (long)n * 64 + ks * 32 + q * 8 + ii, isb);
            if (q < 2) {
                #pragma unroll
                for (int ii = 0; ii < 8; ii++)
                    Bx[L][j][ii] = (bf16)ldf(WihP[L], (long)n * 16 + q * 8 + ii, isb);
            } else {
                #pragma unroll
                for (int ii = 0; ii < 8; ii++) Bx[L][j][ii] = (bf16)0.0f;
            }
            bias[L][j] = ldf(bihP[L], n, isb) + ldf(bhhP[L], n, isb);
        }
    }

    int lenr[2][4];
    #pragma unroll
    for (int mt = 0; mt < 2; mt++)
        #pragma unroll
        for (int r = 0; r < 4; r++)
            lenr[mt][r] = len_sh[mt * 16 + q * 4 + r];

    float c[2][2][4];
    #pragma unroll
    for (int L = 0; L < 2; L++)
        #pragma unroll
        for (int mt = 0; mt < 2; mt++)
            #pragma unroll
            for (int r = 0; r < 4; r++) c[L][mt][r] = 0.0f;

    __syncthreads();   // xbuf + habuf-zero visible

    // ---------------- recurrent loop ----------------
    for (int t = 0; t < TT; t++) {
        #pragma unroll
        for (int L = 0; L < 2; L++) {
            bf16x8 a0[2], a1[2], a2[2];
            #pragma unroll
            for (int mt = 0; mt < 2; mt++) {
                const bf16* hb = &habuf[L][(mt * 16 + l15) * HROW];
                a0[mt] = *reinterpret_cast<const bf16x8*>(hb + q * 8);
                a1[mt] = *reinterpret_cast<const bf16x8*>(hb + 32 + q * 8);
                a2[mt] = *reinterpret_cast<const bf16x8*>(&xbuf[(t * 32 + mt * 16 + l15) * XROW + q * 8]);
            }
            f32x4 D[2][4];
            #pragma unroll
            for (int mt = 0; mt < 2; mt++) {
                #pragma unroll
                for (int j = 0; j < 4; j++) {
                    f32x4 acc = {bias[L][j], bias[L][j], bias[L][j], bias[L][j]};
                    acc = MFMA(a0[mt], Bh[L][j][0], acc);
                    acc = MFMA(a1[mt], Bh[L][j][1], acc);
                    acc = MFMA(a2[mt], Bx[L][j],    acc);
                    D[mt][j] = acc;
                }
            }
            __syncthreads();   // reads of habuf[L] done before writes
            #pragma unroll
            for (int mt = 0; mt < 2; mt++) {
                #pragma unroll
                for (int r = 0; r < 4; r++) {
                    if (t < lenr[mt][r]) {
                        float gi = D[mt][0][r], gf = D[mt][1][r];
                        float gg = D[mt][2][r], go = D[mt][3][r];
                        float cn = sigf(gf) * c[L][mt][r] + sigf(gi) * tanh_fast(gg);
                        c[L][mt][r] = cn;
                        float hn = sigf(go) * tanh_fast(cn);
                        habuf[L][(mt * 16 + q * 4 + r) * HROW + u16] = (bf16)hn;
                    }
                }
            }
        }
    }
    __syncthreads();   // habuf holds h_{len-1} for both LSTMs

    // ---------------- attention scores: leaky_relu(h_a . attn_w) ----------------
    {
        int j = tid >> 3, c8 = tid & 7;
        float p = 0.0f;
        #pragma unroll
        for (int i = 0; i < 8; i++)
            p += (float)habuf[1][j * HROW + c8 * 8 + i] * attn_f[c8 * 8 + i];
        p += __shfl_xor(p, 1);
        p += __shfl_xor(p, 2);
        p += __shfl_xor(p, 4);
        if (c8 == 0) scores_sh[j] = (p > 0.0f) ? p : 0.01f * p;
    }

    // ---------------- m = relu([h_src | h_e] @ edge_out_W^T + b) via MFMA ----------------
    float mval[2][4];
    {
        bf16x8 Bw[4];
        #pragma unroll
        for (int ks = 0; ks < 4; ks++)
            #pragma unroll
            for (int ii = 0; ii < 8; ii++)
                Bw[ks][ii] = (bf16)ldf(edge_out_W, (long)u16 * 128 + ks * 32 + q * 8 + ii, isb);
        float mb = ldf(edge_out_b, u16, isb);
        #pragma unroll
        for (int mt = 0; mt < 2; mt++) {
            const bf16* hs = &hsrc[(mt * 16 + l15) * HROW];
            const bf16* he = &habuf[0][(mt * 16 + l15) * HROW];
            bf16x8 a0 = *reinterpret_cast<const bf16x8*>(hs + q * 8);
            bf16x8 a1 = *reinterpret_cast<const bf16x8*>(hs + 32 + q * 8);
            bf16x8 a2 = *reinterpret_cast<const bf16x8*>(he + q * 8);
            bf16x8 a3 = *reinterpret_cast<const bf16x8*>(he + 32 + q * 8);
            f32x4 acc = {mb, mb, mb, mb};
            acc = MFMA(a0, Bw[0], acc);
            acc = MFMA(a1, Bw[1], acc);
            acc = MFMA(a2, Bw[2], acc);
            acc = MFMA(a3, Bw[3], acc);
            #pragma unroll
            for (int r = 0; r < 4; r++) mval[mt][r] = fmaxf(acc[r], 0.0f);
        }
    }
    __syncthreads();   // scores_sh complete

    // ---------------- sparsemax over 32 (wave 0), reference-exact ----------------
    if (tid < 64) {
        float z = (tid < 32) ? scores_sh[tid] : -3.0e38f;
        float zm = z;
        #pragma unroll
        for (int m = 32; m >= 1; m >>= 1) zm = fmaxf(zm, __shfl_xor(zm, m));
        z -= zm;
        int cnt = 0; float sb = 0.0f;
        for (int i = 0; i < 32; i++) {
            float zi = __shfl(z, i);
            bool before = (zi > z) || (zi == z && i < tid);
            if (before) { cnt++; sb += zi; }
        }
        float r = (float)(cnt + 1);
        float S = sb + z;                      // descending cumsum at this rank
        bool isgt = (tid < 32) && (1.0f + r * z > S);
        float kf  = isgt ? r : 0.0f;
        float sgt = isgt ? z : 0.0f;
        #pragma unroll
        for (int m = 32; m >= 1; m >>= 1) kf = fmaxf(kf, __shfl_xor(kf, m));
        #pragma unroll
        for (int m = 32; m >= 1; m >>= 1) sgt += __shfl_xor(sgt, m);
        float tau = (sgt - 1.0f) / fmaxf(kf, 1.0f);
        if (tid < 32) alpha_sh[tid] = fmaxf(z - tau, 0.0f);
    }
    __syncthreads();

    // ---------------- h_neigh = sum_k alpha_k * m_k ----------------
    {
        float hn = 0.0f;
        #pragma unroll
        for (int mt = 0; mt < 2; mt++)
            #pragma unroll
            for (int r = 0; r < 4; r++)
                hn += alpha_sh[mt * 16 + q * 4 + r] * mval[mt][r];
        hn += __shfl_xor(hn, 16);
        hn += __shfl_xor(hn, 32);
        if (q == 0) vbuf[64 + u16] = hn;
    }
    __syncthreads();

    // ---------------- out = relu([h_dst | h_neigh] @ node_W^T + node_b) ----------------
    {
        int u = tid & 63, kq = w;
        float acc = 0.0f;
        #pragma unroll
        for (int g = 0; g < 4; g++)
            #pragma unroll
            for (int ii = 0; ii < 8; ii++)
                acc += ldf(node_W, (long)u * 128 + kq * 32 + g * 8 + ii, isb) * vbuf[kq * 32 + g * 8 + ii];
        part_sh[kq * 64 + u] = acc;
    }
    __syncthreads();
    if (tid < 64) {
        float s = part_sh[tid] + part_sh[64 + tid] + part_sh[128 + tid] + part_sh[192 + tid]
                + ldf(node_b, tid, isb);
        float v = fmaxf(s, 0.0f);
        long o = (long)d * 64 + tid;
        if (isb) ((bf16*)outp)[o] = (bf16)v;
        else     ((float*)outp)[o] = v;
    }
}

extern "C" void kernel_launch(void* const* d_in, const int* in_sizes, int n_in,
                              void* d_out, int out_size, void* d_ws, size_t ws_size,
                              hipStream_t stream) {
    gtea_fused<<<N_DSTN, 256, 0, stream>>>(
        d_in[0], d_in[1], d_in[2],
        (const int*)d_in[3], (const int*)d_in[4],
        d_in[5], d_in[6], d_in[7], d_in[8],
        d_in[9], d_in[10], d_in[11], d_in[12],
        d_in[13], d_in[14], d_in[15], d_in[16],
        d_in[17], d_in[18], d_in[19],
        d_in[20], d_in[21],
        d_out);
}

// Round 3
// 781.029 us; speedup vs baseline: 2.0707x; 2.0707x over previous
//
#include <hip/hip_runtime.h>

typedef __bf16 bf16;
typedef __bf16 bf16x8 __attribute__((ext_vector_type(8)));
typedef float f32x4 __attribute__((ext_vector_type(4)));

#define N_DSTN 8192
#define TT 16
#define HROW 72            // shorts per h row (64 + 8 pad)
#define HBUF (32 * HROW)   // one parity buffer, in shorts

__device__ __forceinline__ float sigf(float x) {
    float e = __builtin_amdgcn_exp2f(-1.44269504f * x);
    return __builtin_amdgcn_rcpf(1.0f + e);
}
__device__ __forceinline__ float tanh_fast(float x) {
    float e = __builtin_amdgcn_exp2f(2.88539008f * x);
    return 1.0f - 2.0f * __builtin_amdgcn_rcpf(1.0f + e);
}
__device__ __forceinline__ f32x4 MFMA(bf16x8 a, bf16x8 b, f32x4 c) {
    return __builtin_amdgcn_mfma_f32_16x16x32_bf16(a, b, c, 0, 0, 0);
}
__device__ __forceinline__ float ldf(const void* p, long i, bool isb) {
    return isb ? (float)((const bf16*)p)[i] : ((const float*)p)[i];
}
__device__ __forceinline__ bf16x8 zero8() {
    bf16x8 z;
    #pragma unroll
    for (int i = 0; i < 8; i++) z[i] = (bf16)0.0f;
    return z;
}
// 8 consecutive elements as bf16x8; i must be a multiple of 4
__device__ __forceinline__ bf16x8 ld8v(const void* p, long i, bool isb) {
    if (isb) {
        return *reinterpret_cast<const bf16x8*>((const bf16*)p + i);
    } else {
        const float* f = (const float*)p + i;
        float4 u = *reinterpret_cast<const float4*>(f);
        float4 v = *reinterpret_cast<const float4*>(f + 4);
        bf16x8 r;
        r[0] = (bf16)u.x; r[1] = (bf16)u.y; r[2] = (bf16)u.z; r[3] = (bf16)u.w;
        r[4] = (bf16)v.x; r[5] = (bf16)v.y; r[6] = (bf16)v.z; r[7] = (bf16)v.w;
        return r;
    }
}

extern "C" __global__ void __launch_bounds__(512, 4)
gtea_fused(const void* __restrict__ node_features,
           const void* __restrict__ edge_feats,
           const void* __restrict__ e_times,
           const int*  __restrict__ e_len,
           const int*  __restrict__ edge_src,
           const void* __restrict__ t2v_w,
           const void* __restrict__ t2v_b,
           const void* __restrict__ t2v_w0,
           const void* __restrict__ t2v_b0,
           const void* __restrict__ Wih_e,
           const void* __restrict__ Whh_e,
           const void* __restrict__ bih_e,
           const void* __restrict__ bhh_e,
           const void* __restrict__ Wih_a,
           const void* __restrict__ Whh_a,
           const void* __restrict__ bih_a,
           const void* __restrict__ bhh_a,
           const void* __restrict__ attn_w,
           const void* __restrict__ edge_out_W,
           const void* __restrict__ edge_out_b,
           const void* __restrict__ node_W,
           const void* __restrict__ node_b,
           void* __restrict__ outp)
{
    __shared__ __align__(16) bf16 habuf[2][2][HBUF];   // [L][parity]  18432 B
    __shared__ __align__(16) bf16 hsrc[32 * HROW];     // 4608 B
    __shared__ __align__(16) bf16 featb[TT * 32 * 8];  // 8192 B
    __shared__ __align__(16) bf16 tb[TT * 32 * 8];     // 8192 B
    __shared__ float t2w[8], t2b[8];
    __shared__ float attn_f[64];
    __shared__ float vbuf[128];
    __shared__ float part_sh[4 * 64];
    __shared__ float scores_sh[32], alpha_sh[32];
    __shared__ int   len0_sh[32], lens_sh[32], idx_sh[32];
    __shared__ int   isb_sh;

    const int tid = threadIdx.x;
    const int w   = tid >> 6;
    const int l   = tid & 63;
    const int l15 = l & 15;
    const int q   = l >> 4;
    const int L   = w >> 2;          // 0: lstm_e, 1: lstm_a
    const int w4  = w & 3;
    const int u16 = w4 * 16 + l15;

    const int d  = blockIdx.x;
    const int e0 = d * 32;

    // ---- dtype sniff ----
    if (tid < 64) {
        const unsigned short* u = (const unsigned short*)e_times;
        unsigned short a = u[tid * 2], b = u[tid * 2 + 1];
        bool ok = (a <= 0x3F80u) && (b <= 0x3F80u);
        unsigned long long m = __ballot(ok);
        if (tid == 0) isb_sh = (m == ~0ULL) ? 1 : 0;
    }
    if (tid < 32) len0_sh[tid] = e_len[e0 + tid];
    __syncthreads();
    const bool isb = (isb_sh != 0);

    // ---- S0: params, h_dst, habuf zero, sort ----
    if (tid < 7)  { t2w[tid] = ldf(t2v_w, tid, isb); t2b[tid] = ldf(t2v_b, tid, isb); }
    if (tid == 7) { t2w[7] = ldf(t2v_w0, 0, isb); t2b[7] = ldf(t2v_b0, 0, isb); }
    if (tid < 64) attn_f[tid] = ldf(attn_w, tid, isb);
    if (tid < 64) vbuf[tid] = ldf(node_features, (long)d * 64 + tid, isb);
    {
        unsigned int* hz = reinterpret_cast<unsigned int*>(&habuf[0][0][0]);
        for (int i = tid; i < 2 * 2 * HBUF / 2; i += 512) hz[i] = 0u;
    }
    if (tid < 32) {
        int lj = len0_sh[tid];
        int rank = 0;
        for (int i = 0; i < 32; i++) {
            int li = len0_sh[i];
            rank += (li > lj) || (li == lj && i < tid);
        }
        int mt = rank >> 4, kp = rank & 15;
        int slot = mt * 16 + (kp & 3) * 4 + (kp >> 2);
        idx_sh[slot]  = tid;
        lens_sh[slot] = lj;
    }
    __syncthreads();

    // ---- S2: edge staging + weights ----
    int gm0[4], gm1[4];
    #pragma unroll
    for (int r = 0; r < 4; r++) {
        gm0[r] = __builtin_amdgcn_readfirstlane(lens_sh[r]);
        gm1[r] = __builtin_amdgcn_readfirstlane(lens_sh[16 + r]);
    }
    const int tmax = gm0[0], mtmax1 = gm1[0];

    unsigned lp = 0;
    #pragma unroll
    for (int mt = 0; mt < 2; mt++)
        #pragma unroll
        for (int r = 0; r < 4; r++)
            lp |= (unsigned)(lens_sh[mt * 16 + q * 4 + r] - 1) << ((mt * 4 + r) * 4);

    if (tid < 256) {
        int s = tid >> 3, c8 = tid & 7;
        int src = edge_src[e0 + idx_sh[s]];
        *reinterpret_cast<bf16x8*>(&hsrc[s * HROW + c8 * 8]) =
            ld8v(node_features, (long)src * 64 + c8 * 8, isb);
    }
    {
        int s = tid >> 4, t = tid & 15;
        int j = idx_sh[s];
        long base = ((long)(e0 + j) * TT + t) * 8;
        *reinterpret_cast<bf16x8*>(&featb[(t * 32 + s) * 8]) = ld8v(edge_feats, base, isb);
        float tau = ldf(e_times, (long)(e0 + j) * TT + t, isb);
        bf16x8 te;
        #pragma unroll
        for (int i = 0; i < 7; i++) te[i] = (bf16)__sinf(tau * t2w[i] + t2b[i]);
        te[7] = (bf16)(tau * t2w[7] + t2b[7]);
        *reinterpret_cast<bf16x8*>(&tb[(t * 32 + s) * 8]) = te;
    }

    const void* Whh = L ? Whh_a : Whh_e;
    const void* Wih = L ? Wih_a : Wih_e;
    const void* bih = L ? bih_a : bih_e;
    const void* bhh = L ? bhh_a : bhh_e;
    bf16x8 Bh[4][2], Bx[4];
    float  bias[4];
    #pragma unroll
    for (int j = 0; j < 4; j++) {
        int n = 64 * j + u16;
        Bh[j][0] = ld8v(Whh, (long)n * 64 + q * 8, isb);
        Bh[j][1] = ld8v(Whh, (long)n * 64 + 32 + q * 8, isb);
        Bx[j] = (q < 2) ? ld8v(Wih, (long)n * 16 + q * 8, isb) : zero8();
        bias[j] = ldf(bih, n, isb) + ldf(bhh, n, isb);
    }

    float c[2][4];
    #pragma unroll
    for (int mt = 0; mt < 2; mt++)
        #pragma unroll
        for (int r = 0; r < 4; r++) c[mt][r] = 0.0f;

    __syncthreads();

    // ---- recurrent loop: double-buffered h, 1 barrier/step ----
    bf16* hb_base = &habuf[L][0][0];
    for (int t = 0; t < tmax; t++) {
        const bf16* hbR = hb_base + (t & 1) * HBUF;
        bf16*       hbW = hb_base + ((t + 1) & 1) * HBUF;

        auto do_mt = [&](int mt) {
            const bf16* hr = hbR + (mt * 16 + l15) * HROW;
            bf16x8 ah0 = *reinterpret_cast<const bf16x8*>(hr + q * 8);
            bf16x8 ah1 = *reinterpret_cast<const bf16x8*>(hr + 32 + q * 8);
            bf16x8 xa;
            if (q < 2) {
                const bf16* xp = (q == 0 ? featb : tb) + (t * 32 + mt * 16 + l15) * 8;
                xa = *reinterpret_cast<const bf16x8*>(xp);
            } else {
                xa = zero8();
            }
            f32x4 D[4];
            #pragma unroll
            for (int j = 0; j < 4; j++) {
                f32x4 acc = {bias[j], bias[j], bias[j], bias[j]};
                acc = MFMA(ah0, Bh[j][0], acc);
                acc = MFMA(ah1, Bh[j][1], acc);
                acc = MFMA(xa,  Bx[j],    acc);
                D[j] = acc;
            }
            #pragma unroll
            for (int r = 0; r < 4; r++) {
                int gmax = mt ? gm1[r] : gm0[r];
                if (t < gmax) {
                    int lm1 = (int)((lp >> ((mt * 4 + r) * 4)) & 15u);
                    if (t <= lm1) {
                        float gi = D[0][r], gf = D[1][r];
                        float gg = D[2][r], go = D[3][r];
                        float cn = sigf(gf) * c[mt][r] + sigf(gi) * tanh_fast(gg);
                        c[mt][r] = cn;
                        float hn = sigf(go) * tanh_fast(cn);
                        hbW[(mt * 16 + q * 4 + r) * HROW + u16] = (bf16)hn;
                    }
                }
            }
        };
        do_mt(0);
        if (t < mtmax1) do_mt(1);
        __syncthreads();
    }

    // ---- epilogue ----
    if (tid < 256) {   // attention scores
        int s = tid >> 3, c8 = tid & 7;
        const bf16* ha = &habuf[1][lens_sh[s] & 1][s * HROW];
        float p = 0.0f;
        #pragma unroll
        for (int i = 0; i < 8; i++)
            p += (float)ha[c8 * 8 + i] * attn_f[c8 * 8 + i];
        p += __shfl_xor(p, 1);
        p += __shfl_xor(p, 2);
        p += __shfl_xor(p, 4);
        if (c8 == 0) scores_sh[s] = (p > 0.0f) ? p : 0.01f * p;
    }
    float mval[2][4];
    if (tid < 256) {   // m = relu([h_src | h_e] @ edge_out_W^T + b)
        bf16x8 Bw[4];
        #pragma unroll
        for (int ks = 0; ks < 4; ks++)
            Bw[ks] = ld8v(edge_out_W, (long)u16 * 128 + ks * 32 + q * 8, isb);
        float mb = ldf(edge_out_b, u16, isb);
        #pragma unroll
        for (int mt = 0; mt < 2; mt++) {
            int s = mt * 16 + l15;
            const bf16* hs = &hsrc[s * HROW];
            const bf16* he = &habuf[0][lens_sh[s] & 1][s * HROW];
            bf16x8 a0 = *reinterpret_cast<const bf16x8*>(hs + q * 8);
            bf16x8 a1 = *reinterpret_cast<const bf16x8*>(hs + 32 + q * 8);
            bf16x8 a2 = *reinterpret_cast<const bf16x8*>(he + q * 8);
            bf16x8 a3 = *reinterpret_cast<const bf16x8*>(he + 32 + q * 8);
            f32x4 acc = {mb, mb, mb, mb};
            acc = MFMA(a0, Bw[0], acc);
            acc = MFMA(a1, Bw[1], acc);
            acc = MFMA(a2, Bw[2], acc);
            acc = MFMA(a3, Bw[3], acc);
            #pragma unroll
            for (int r = 0; r < 4; r++) mval[mt][r] = fmaxf(acc[r], 0.0f);
        }
    }
    __syncthreads();

    if (tid < 64) {   // sparsemax (reference-exact)
        float z = (tid < 32) ? scores_sh[tid] : -3.0e38f;
        float zm = z;
        #pragma unroll
        for (int m = 32; m >= 1; m >>= 1) zm = fmaxf(zm, __shfl_xor(zm, m));
        z -= zm;
        int cnt = 0; float sb = 0.0f;
        for (int i = 0; i < 32; i++) {
            float zi = __shfl(z, i);
            bool before = (zi > z) || (zi == z && i < tid);
            if (before) { cnt++; sb += zi; }
        }
        float r = (float)(cnt + 1);
        float S = sb + z;
        bool isgt = (tid < 32) && (1.0f + r * z > S);
        float kf  = isgt ? r : 0.0f;
        float sgt = isgt ? z : 0.0f;
        #pragma unroll
        for (int m = 32; m >= 1; m >>= 1) kf = fmaxf(kf, __shfl_xor(kf, m));
        #pragma unroll
        for (int m = 32; m >= 1; m >>= 1) sgt += __shfl_xor(sgt, m);
        float tau = (sgt - 1.0f) / fmaxf(kf, 1.0f);
        if (tid < 32) alpha_sh[tid] = fmaxf(z - tau, 0.0f);
    }
    __syncthreads();

    if (tid < 256) {   // h_neigh
        float hn = 0.0f;
        #pragma unroll
        for (int mt = 0; mt < 2; mt++)
            #pragma unroll
            for (int r = 0; r < 4; r++)
                hn += alpha_sh[mt * 16 + q * 4 + r] * mval[mt][r];
        hn += __shfl_xor(hn, 16);
        hn += __shfl_xor(hn, 32);
        if (q == 0) vbuf[64 + u16] = hn;
    }
    __syncthreads();

    if (tid < 256) {   // final matvec partials
        int u = tid & 63, kq = w;
        bf16x8 wv0 = ld8v(node_W, (long)u * 128 + kq * 32, isb);
        bf16x8 wv1 = ld8v(node_W, (long)u * 128 + kq * 32 + 8, isb);
        bf16x8 wv2 = ld8v(node_W, (long)u * 128 + kq * 32 + 16, isb);
        bf16x8 wv3 = ld8v(node_W, (long)u * 128 + kq * 32 + 24, isb);
        float acc = 0.0f;
        #pragma unroll
        for (int i = 0; i < 8; i++) {
            acc += (float)wv0[i] * vbuf[kq * 32 + i];
            acc += (float)wv1[i] * vbuf[kq * 32 + 8 + i];
            acc += (float)wv2[i] * vbuf[kq * 32 + 16 + i];
            acc += (float)wv3[i] * vbuf[kq * 32 + 24 + i];
        }
        part_sh[kq * 64 + u] = acc;
    }
    __syncthreads();
    if (tid < 64) {
        float s = part_sh[tid] + part_sh[64 + tid] + part_sh[128 + tid] + part_sh[192 + tid]
                + ldf(node_b, tid, isb);
        float v = fmaxf(s, 0.0f);
        long o = (long)d * 64 + tid;
        if (isb) ((bf16*)outp)[o] = (bf16)v;
        else     ((float*)outp)[o] = v;
    }
}

extern "C" void kernel_launch(void* const* d_in, const int* in_sizes, int n_in,
                              void* d_out, int out_size, void* d_ws, size_t ws_size,
                              hipStream_t stream) {
    gtea_fused<<<N_DSTN, 512, 0, stream>>>(
        d_in[0], d_in[1], d_in[2],
        (const int*)d_in[3], (const int*)d_in[4],
        d_in[5], d_in[6], d_in[7], d_in[8],
        d_in[9], d_in[10], d_in[11], d_in[12],
        d_in[13], d_in[14], d_in[15], d_in[16],
        d_in[17], d_in[18], d_in[19],
        d_in[20], d_in[21],
        d_out);
}